// Round 4
// baseline (395.492 us; speedup 1.0000x reference)
//
#include <hip/hip_runtime.h>

typedef __attribute__((ext_vector_type(8))) short short8;
typedef __attribute__((ext_vector_type(16))) float f32x16;

#define B_    8
#define CI    256
#define CO    256
#define Hh    160
#define Ww    160
#define HP    162
#define WP    162
#define HWp   (Hh * Ww)                 // 25600
#define XPAD_ELEMS (B_ * HP * WP * CI)  // 53,747,712 bf16
#define W2_ELEMS   (9 * CI * CO)        // 589,824 bf16
#define NT    36                        // 4 ci-chunks (outer) x 9 shifts (inner)
// LDS slot: A[128][64] + B[256][64] bf16
#define ASZ   (128 * 64)                // 8192 shorts
#define SLOT  (ASZ + 256 * 64)          // 24576 shorts = 48 KB

__device__ __forceinline__ unsigned short f2bf(float f) {
  unsigned int u = __float_as_uint(f);
  u += 0x7FFFu + ((u >> 16) & 1u);   // RNE
  return (unsigned short)(u >> 16);
}

// weight [co][ci][3][3] f32 -> w2 [shift][co][ci] bf16 (ci contiguous)
__global__ void prep_w_kernel(const float* __restrict__ w, unsigned short* __restrict__ w2) {
  int i = blockIdx.x * 256 + threadIdx.x;
  if (i >= W2_ELEMS) return;
  int ci = i & 255;
  int t = i >> 8;
  int co = t & 255;
  int s = t >> 8;
  w2[i] = f2bf(w[(co * 256 + ci) * 9 + s]);
}

// zero the padded border of xp
__global__ void zero_border(unsigned short* __restrict__ xp) {
  int g = blockIdx.x * 256 + threadIdx.x;
  int pos = g >> 5;
  int c = (g & 31) << 3;
  int n = pos / 644;
  int p = pos - n * 644;
  int y, x;
  if (p < 324) { y = (p < 162) ? 0 : 161; x = (p < 162) ? p : p - 162; }
  else { int q = p - 324; y = 1 + (q >> 1); x = (q & 1) ? 161 : 0; }
  unsigned short* d = xp + (((size_t)(n * 162 + y)) * 162 + x) * 256 + c;
  *(uint4*)d = (uint4){0u, 0u, 0u, 0u};
}

// ori [n][ci][h][w] f32 * mask -> xp [n][h+1][w+1][ci] bf16 (padded NHWC)
__global__ void prep_x_kernel(const float* __restrict__ ori, const int* __restrict__ mask,
                              unsigned short* __restrict__ xp) {
  int bid = blockIdx.x;                 // ((n*160+h)*4+cit)*3+wt
  int wt = bid % 3;
  int t1 = bid / 3;
  int cit = t1 & 3;
  int t2 = t1 >> 2;
  int h = t2 % Hh;
  int n = t2 / Hh;
  int t = threadIdx.x;

  __shared__ float tile[64][65];

  int wl = t & 63;
  int w = wt * 64 + wl;
  bool valid = (w < Ww);
  float m = 0.f;
  if (valid) m = (float)mask[(n * Hh + h) * Ww + w];
  const float* src = ori + (((size_t)(n * CI + cit * 64) * Hh + h) * Ww + w);
  int r0 = t >> 6;
#pragma unroll
  for (int k = 0; k < 16; ++k) {
    int ci_l = r0 * 16 + k;
    float v = 0.f;
    if (valid) v = src[(size_t)ci_l * HWp] * m;
    tile[ci_l][wl] = v;
  }
  __syncthreads();

  int wl2 = t >> 2;
  int wo = wt * 64 + wl2;
  if (wo < Ww) {
    int cseg = (t & 3) * 16;
    union { unsigned short u[8]; uint4 v; } p0, p1;
#pragma unroll
    for (int j = 0; j < 8; ++j) p0.u[j] = f2bf(tile[cseg + j][wl2]);
#pragma unroll
    for (int j = 0; j < 8; ++j) p1.u[j] = f2bf(tile[cseg + 8 + j][wl2]);
    unsigned short* dst = xp + ((size_t)((n * HP + h + 1) * WP) + (wo + 1)) * CI + cit * 64 + cseg;
    *(uint4*)dst = p0.v;
    *(uint4*)(dst + 8) = p1.v;
  }
}

__device__ __forceinline__ void gload16(const unsigned short* g, unsigned short* l) {
  __builtin_amdgcn_global_load_lds((const __attribute__((address_space(1))) void*)g,
                                   (__attribute__((address_space(3))) void*)l, 16, 0, 0);
}

// Implicit GEMM, 32x32x16 MFMA, both operands LDS, 3-slot ring + counted vmcnt.
// Block: 128co x 256px, 512 thr = 8 waves (2m x 4n), wave 64co x 64px, acc[2][2] f32x16.
// Tile order: ci-chunk OUTER, shift INNER (tt = cic*9 + shift) for L2 locality.
// Stage(tt+2) issued at TOP of tile tt into slot (tt+2)%3 (disjoint from tt, tt+1);
// inter-tile barrier waits vmcnt(6) -> stage(tt+2)'s 6 gloads stay in flight.
__global__ void __launch_bounds__(512, 1) sconv_gemm(const unsigned short* __restrict__ xp,
                                                     const unsigned short* __restrict__ w2,
                                                     const float* __restrict__ bias,
                                                     float* __restrict__ out) {
  __shared__ unsigned short lds[3 * SLOT];   // 144 KB

  // 1600 blocks = 8 XCD-chunks of 200; XCD k owns image k.
  int raw = blockIdx.x;
  int n = raw & 7;
  int seq = raw >> 3;               // 0..199
  int cot = seq & 1;                // co half; raw-pairs share the same px-tile (B L2-hit)
  int pxt = seq >> 1;               // 0..99 px-tile within image
  const int co0 = cot * 128;
  const int hw0 = pxt * 256;

  const int t = threadIdx.x;
  const int l = t & 63;
  const int wv = t >> 6;
  const int wm = wv >> 2;           // 0..1 co half-of-block (64 co)
  const int wn = wv & 3;            // 0..3 px quarter (64 px)

  // staging swizzle: lane covers LDS row (base + l>>3), 16B slot (l&7);
  // global source slot pre-swizzled: (l&7)^(l>>3)
  const int lr = l >> 3;
  const int swz8 = ((l & 7) ^ lr) << 3;
  unsigned aoff[2];
#pragma unroll
  for (int g = 0; g < 2; ++g)
    aoff[g] = (unsigned)(co0 + wv * 16 + g * 8 + lr) * 256 + swz8;
  unsigned boff[4];
#pragma unroll
  for (int g = 0; g < 4; ++g) {
    int hw = hw0 + wv * 32 + g * 8 + lr;
    int h = hw / Ww;
    int w = hw - h * Ww;
    boff[g] = (unsigned)((n * HP + h) * WP + w) * 256 + swz8;
  }

  f32x16 acc[2][2];
#pragma unroll
  for (int mi = 0; mi < 2; ++mi)
#pragma unroll
    for (int ni = 0; ni < 2; ++ni)
      acc[mi][ni] = (f32x16)(0.f);

  auto STAGE = [&](int tt) {
    int cic = (tt * 57) >> 9;            // tt/9 for tt<36
    int shift = tt - cic * 9;
    int kh = (shift * 11) >> 5;          // shift/3
    int kw = shift - kh * 3;
    unsigned ad = (unsigned)shift * (CI * CO) + (cic << 6);
    unsigned bd = (unsigned)(kh * WP + kw) * 256 + (cic << 6);
    unsigned short* s = &lds[(tt % 3) * SLOT];
#pragma unroll
    for (int g = 0; g < 2; ++g)
      gload16(w2 + ad + aoff[g], s + (wv * 16 + g * 8) * 64);
#pragma unroll
    for (int g = 0; g < 4; ++g)
      gload16(xp + bd + boff[g], s + ASZ + (wv * 32 + g * 8) * 64);
  };

  // prologue: fill slots 0,1; wait own slot-0 gloads only (slot-1's 6 stay in flight)
  STAGE(0);
  STAGE(1);
  asm volatile("s_waitcnt vmcnt(6)" ::: "memory");
  __builtin_amdgcn_s_barrier();

  const int l31 = l & 31;
  const int bhi = l >> 5;
  const int lx = l & 7;

  for (int tt = 0; tt < NT; ++tt) {
    if (tt + 2 < NT) STAGE(tt + 2);     // issued early -> flies across this whole tile

    const unsigned short* A = &lds[(tt % 3) * SLOT];
    const unsigned short* Bb = A + ASZ;
    const unsigned short* ar = A + (wm * 64 + l31) * 64;
    const unsigned short* br = Bb + (wn * 64 + l31) * 64;

#pragma unroll
    for (int s = 0; s < 4; ++s) {
      int so = (((s << 1) + bhi) ^ lx) << 3;
      short8 a0 = *(const short8*)(ar + so);
      short8 a1 = *(const short8*)(ar + 32 * 64 + so);
      short8 b0 = *(const short8*)(br + so);
      short8 b1 = *(const short8*)(br + 32 * 64 + so);
      __builtin_amdgcn_s_setprio(1);
      acc[0][0] = __builtin_amdgcn_mfma_f32_32x32x16_bf16(a0, b0, acc[0][0], 0, 0, 0);
      acc[0][1] = __builtin_amdgcn_mfma_f32_32x32x16_bf16(a0, b1, acc[0][1], 0, 0, 0);
      acc[1][0] = __builtin_amdgcn_mfma_f32_32x32x16_bf16(a1, b0, acc[1][0], 0, 0, 0);
      acc[1][1] = __builtin_amdgcn_mfma_f32_32x32x16_bf16(a1, b1, acc[1][1], 0, 0, 0);
      __builtin_amdgcn_s_setprio(0);
    }

    // counted drain: stage(tt+1) (issued 2 tiles ago) must land; stage(tt+2) stays out
    if (tt == 34)
      asm volatile("s_waitcnt vmcnt(0) lgkmcnt(0)" ::: "memory");
    else
      asm volatile("s_waitcnt vmcnt(6) lgkmcnt(0)" ::: "memory");
    __builtin_amdgcn_s_barrier();
  }

  // epilogue: D col(px)=l&31, row(co)=(q&3)+8*(q>>2)+4*(l>>5)
#pragma unroll
  for (int mi = 0; mi < 2; ++mi) {
    int cobase = co0 + wm * 64 + mi * 32 + 4 * bhi;
#pragma unroll
    for (int ni = 0; ni < 2; ++ni) {
      int px = hw0 + wn * 64 + ni * 32 + l31;
      float* op = out + ((size_t)n * CO) * HWp + px;
      f32x16 v = acc[mi][ni];
#pragma unroll
      for (int g = 0; g < 4; ++g) {
        int co = cobase + 8 * g;
        const float4 bv = *(const float4*)(bias + co);
#pragma unroll
        for (int r = 0; r < 4; ++r)
          op[(size_t)(co + r) * HWp] = v[g * 4 + r] + ((const float*)&bv)[r];
      }
    }
  }
}

extern "C" void kernel_launch(void* const* d_in, const int* in_sizes, int n_in,
                              void* d_out, int out_size, void* d_ws, size_t ws_size,
                              hipStream_t stream) {
  const int* mask = (const int*)d_in[0];
  const float* ori = (const float*)d_in[1];
  const float* weight = (const float*)d_in[2];
  const float* bias = (const float*)d_in[3];
  float* out = (float*)d_out;

  unsigned short* xp = (unsigned short*)d_ws;          // padded NHWC bf16, 107.5 MB
  unsigned short* w2 = xp + XPAD_ELEMS;                // 1.2 MB

  zero_border<<<644, 256, 0, stream>>>(xp);
  prep_w_kernel<<<(W2_ELEMS + 255) / 256, 256, 0, stream>>>(weight, w2);
  prep_x_kernel<<<B_ * Hh * 4 * 3, 256, 0, stream>>>(ori, mask, xp);
  sconv_gemm<<<1600, 512, 0, stream>>>(xp, w2, bias, out);
}

// Round 5
// 361.023 us; speedup vs baseline: 1.0955x; 1.0955x over previous
//
#include <hip/hip_runtime.h>

typedef __attribute__((ext_vector_type(8))) short short8;
typedef __attribute__((ext_vector_type(4))) float f32x4;

#define B_    8
#define CI    256
#define CO    256
#define Hh    160
#define Ww    160
#define HP    162
#define WP    162
#define HWp   (Hh * Ww)                 // 25600
#define XPAD_ELEMS (B_ * HP * WP * CI)  // 53,747,712 bf16
#define W2_ELEMS   (9 * CI * CO)        // 589,824 bf16
// GEMM geometry: block 128co x 640px (4 image rows), 512 thr = 8 waves,
// wave = 64co x 160px (one image row), acc[4][10] f32x4.
// K: 4 ci-chunks (outer) x 9 shifts (inner), K=64 per substep.
// LDS: A dbuf 2x[128][64] = 32KB at 0; B strip [6 rows][168 units][64ci] at SOFF.
#define SOFF  16384                     // shorts: strip base (A dbuf = 2*8192)
#define SROW  (168 * 64)                // shorts per strip row (10752)

__device__ __forceinline__ unsigned short f2bf(float f) {
  unsigned int u = __float_as_uint(f);
  u += 0x7FFFu + ((u >> 16) & 1u);   // RNE
  return (unsigned short)(u >> 16);
}

// weight [co][ci][3][3] f32 -> w2 [shift][co][ci] bf16 (ci contiguous)
__global__ void prep_w_kernel(const float* __restrict__ w, unsigned short* __restrict__ w2) {
  int i = blockIdx.x * 256 + threadIdx.x;
  if (i >= W2_ELEMS) return;
  int ci = i & 255;
  int t = i >> 8;
  int co = t & 255;
  int s = t >> 8;
  w2[i] = f2bf(w[(co * 256 + ci) * 9 + s]);
}

// zero the padded border of xp
__global__ void zero_border(unsigned short* __restrict__ xp) {
  int g = blockIdx.x * 256 + threadIdx.x;
  int pos = g >> 5;
  int c = (g & 31) << 3;
  int n = pos / 644;
  int p = pos - n * 644;
  int y, x;
  if (p < 324) { y = (p < 162) ? 0 : 161; x = (p < 162) ? p : p - 162; }
  else { int q = p - 324; y = 1 + (q >> 1); x = (q & 1) ? 161 : 0; }
  unsigned short* d = xp + (((size_t)(n * 162 + y)) * 162 + x) * 256 + c;
  *(uint4*)d = (uint4){0u, 0u, 0u, 0u};
}

// ori [n][ci][h][w] f32 * mask -> xp [n][h+1][w+1][ci] bf16 (padded NHWC)
__global__ void prep_x_kernel(const float* __restrict__ ori, const int* __restrict__ mask,
                              unsigned short* __restrict__ xp) {
  int bid = blockIdx.x;                 // ((n*160+h)*4+cit)*3+wt
  int wt = bid % 3;
  int t1 = bid / 3;
  int cit = t1 & 3;
  int t2 = t1 >> 2;
  int h = t2 % Hh;
  int n = t2 / Hh;
  int t = threadIdx.x;

  __shared__ float tile[64][65];

  int wl = t & 63;
  int w = wt * 64 + wl;
  bool valid = (w < Ww);
  float m = 0.f;
  if (valid) m = (float)mask[(n * Hh + h) * Ww + w];
  const float* src = ori + (((size_t)(n * CI + cit * 64) * Hh + h) * Ww + w);
  int r0 = t >> 6;
#pragma unroll
  for (int k = 0; k < 16; ++k) {
    int ci_l = r0 * 16 + k;
    float v = 0.f;
    if (valid) v = src[(size_t)ci_l * HWp] * m;
    tile[ci_l][wl] = v;
  }
  __syncthreads();

  int wl2 = t >> 2;
  int wo = wt * 64 + wl2;
  if (wo < Ww) {
    int cseg = (t & 3) * 16;
    union { unsigned short u[8]; uint4 v; } p0, p1;
#pragma unroll
    for (int j = 0; j < 8; ++j) p0.u[j] = f2bf(tile[cseg + j][wl2]);
#pragma unroll
    for (int j = 0; j < 8; ++j) p1.u[j] = f2bf(tile[cseg + 8 + j][wl2]);
    unsigned short* dst = xp + ((size_t)((n * HP + h + 1) * WP) + (wo + 1)) * CI + cit * 64 + cseg;
    *(uint4*)dst = p0.v;
    *(uint4*)(dst + 8) = p1.v;
  }
}

__device__ __forceinline__ void gload16(const unsigned short* g, unsigned short* l) {
  __builtin_amdgcn_global_load_lds((const __attribute__((address_space(1))) void*)g,
                                   (__attribute__((address_space(3))) void*)l, 16, 0, 0);
}

__global__ void __launch_bounds__(512, 1) sconv_gemm(const unsigned short* __restrict__ xp,
                                                     const unsigned short* __restrict__ w2,
                                                     const float* __restrict__ bias,
                                                     float* __restrict__ out) {
  __shared__ unsigned short lds[SOFF + 6 * SROW];   // 32KB A-dbuf + 126KB strip = 158KB

  // grid 640 = 8 img (XCD-owned) x 2 co-halves x 40 row-groups
  const int bid = blockIdx.x;
  const int n = bid & 7;
  const int rest = bid >> 3;
  const int cot = rest & 1;
  const int rg = rest >> 1;           // 0..39
  const int r0 = rg * 4;              // first of 4 image rows
  const int co0 = cot * 128;
  const unsigned h0p = (unsigned)(n * HP + r0);   // top padded strip row

  const int t = threadIdx.x;
  const int l = t & 63;
  const int wv = t >> 6;              // 8 waves
  const int wm = wv & 1;              // co half-of-block (64 co)
  const int wn = wv >> 1;             // image row 0..3

  const int lr = l >> 3;
  const int swz8 = ((l & 7) ^ lr) << 3;       // proven source pre-swizzle
  const int lc = l & 15;
  const int hi4 = l >> 4;
  const int lx = l & 7;

  // A stage: rows wv*16 + j*8 + lr, j=0,1
  const unsigned arow0 = (unsigned)(co0 + wv * 16 + lr) * 256 + swz8;
  // A read row base (shorts): row = wm*64 + mi*16 + lc
  const int acu = (wm * 64 + lc) * 64;
  // B read lane base (shorts, rel. SOFF): unit = wn*168 + lc (+ni*16 +kh*168+kw)
  const int bub = wn * SROW + lc * 64;

  f32x4 acc[4][10];
#pragma unroll
  for (int mi = 0; mi < 4; ++mi)
#pragma unroll
    for (int ni = 0; ni < 10; ++ni)
      acc[mi][ni] = (f32x4){0.f, 0.f, 0.f, 0.f};

  auto STAGE_A = [&](int slot, int shift, int cic) {
    const unsigned short* src = w2 + shift * 65536 + (cic << 6) + arow0;
    unsigned short* dst = lds + slot * 8192 + (wv * 16) * 64;
    gload16(src, dst);
    gload16(src + 2048, dst + 512);
  };

  auto STAGE_STRIP = [&](int cic) {
    // 126 granules = 6 rows x 21; wave handles g = wv, wv+8, ...
#pragma unroll
    for (int k = 0; k < 16; ++k) {
      int g = wv + 8 * k;
      if (g < 126) {
        int khr = g / 21;
        int gg = g - khr * 21;
        const unsigned short* src = xp + ((size_t)(h0p + khr) * WP + gg * 8 + lr) * 256
                                       + (cic << 6) + swz8;
        gload16(src, lds + SOFF + khr * SROW + (gg * 8) * 64);
      }
    }
  };

  STAGE_STRIP(0);
  STAGE_A(0, 0, 0);
  asm volatile("s_waitcnt vmcnt(0)" ::: "memory");
  __builtin_amdgcn_s_barrier();

  for (int cic = 0; cic < 4; ++cic) {
    for (int s = 0; s < 9; ++s) {
      const int tt = cic * 9 + s;
      // prefetch next A (flies across this substep's compute)
      if (s < 8) STAGE_A((tt + 1) & 1, s + 1, cic);
      else if (cic < 3) STAGE_A((tt + 1) & 1, 0, cic + 1);

      const int kh = (s >= 6) ? 2 : (s >= 3 ? 1 : 0);
      const int kw = s - kh * 3;
      const unsigned short* As = lds + (tt & 1) * 8192;
      const int koff = SOFF + bub + (kh * 168 + kw) * 64;
      const int xb = (lc + kw) & 7;

#pragma unroll
      for (int kk = 0; kk < 2; ++kk) {
        const int sa = (((kk << 2) + hi4) ^ lx) << 3;
        const int sb = (((kk << 2) + hi4) ^ xb) << 3;
        short8 a[4];
#pragma unroll
        for (int mi = 0; mi < 4; ++mi)
          a[mi] = *(const short8*)(As + acu + mi * 1024 + sa);
#pragma unroll
        for (int ni = 0; ni < 10; ++ni) {
          short8 b = *(const short8*)(lds + koff + ni * 1024 + sb);
          __builtin_amdgcn_s_setprio(1);
#pragma unroll
          for (int mi = 0; mi < 4; ++mi)
            acc[mi][ni] = __builtin_amdgcn_mfma_f32_16x16x32_bf16(a[mi], b, acc[mi][ni], 0, 0, 0);
          __builtin_amdgcn_s_setprio(0);
        }
      }

      if (s == 8 && cic < 3) {
        __builtin_amdgcn_s_barrier();          // all waves done reading strip(cic)
        STAGE_STRIP(cic + 1);
        asm volatile("s_waitcnt vmcnt(0)" ::: "memory");   // strip + A landed
        __builtin_amdgcn_s_barrier();
      } else {
        asm volatile("s_waitcnt vmcnt(0)" ::: "memory");   // next-A landed (flew whole substep)
        __builtin_amdgcn_s_barrier();
      }
    }
  }

  // epilogue: D row=co ((l>>4)*4 + r), col=px (l&15); wave writes image row r0+wn
  const int orow = r0 + wn;
#pragma unroll
  for (int mi = 0; mi < 4; ++mi) {
    int cobase = co0 + wm * 64 + mi * 16 + hi4 * 4;
    const float4 bv = *(const float4*)(bias + cobase);
    float* op = out + (((size_t)n * CO + cobase) * Hh + orow) * Ww;
#pragma unroll
    for (int ni = 0; ni < 10; ++ni) {
      int w = ni * 16 + lc;
      f32x4 v = acc[mi][ni];
      op[w]               = v[0] + bv.x;
      op[(size_t)Hh * Ww + w]     = v[1] + bv.y;
      op[(size_t)2 * Hh * Ww + w] = v[2] + bv.z;
      op[(size_t)3 * Hh * Ww + w] = v[3] + bv.w;
    }
  }
}

extern "C" void kernel_launch(void* const* d_in, const int* in_sizes, int n_in,
                              void* d_out, int out_size, void* d_ws, size_t ws_size,
                              hipStream_t stream) {
  const int* mask = (const int*)d_in[0];
  const float* ori = (const float*)d_in[1];
  const float* weight = (const float*)d_in[2];
  const float* bias = (const float*)d_in[3];
  float* out = (float*)d_out;

  unsigned short* xp = (unsigned short*)d_ws;          // padded NHWC bf16, 107.5 MB
  unsigned short* w2 = xp + XPAD_ELEMS;                // 1.2 MB

  zero_border<<<644, 256, 0, stream>>>(xp);
  prep_w_kernel<<<(W2_ELEMS + 255) / 256, 256, 0, stream>>>(weight, w2);
  prep_x_kernel<<<B_ * Hh * 4 * 3, 256, 0, stream>>>(ori, mask, xp);
  sconv_gemm<<<640, 512, 0, stream>>>(xp, w2, bias, out);
}

// Round 6
// 341.456 us; speedup vs baseline: 1.1582x; 1.0573x over previous
//
#include <hip/hip_runtime.h>

typedef __attribute__((ext_vector_type(8))) short short8;
typedef __attribute__((ext_vector_type(4))) float f32x4;

#define B_    8
#define CI    256
#define CO    256
#define Hh    160
#define Ww    160
#define HP    162
#define WP    162
#define HWp   (Hh * Ww)                 // 25600
#define XPAD_ELEMS (B_ * HP * WP * CI)  // 53,747,712 bf16
#define W3_ELEMS   (9 * CI * CO)        // 589,824 bf16 (granule order)
#define NT    36                        // 4 ci-chunks x 9 shifts, BK=64

__device__ __forceinline__ unsigned short f2bf(float f) {
  unsigned int u = __float_as_uint(f);
  u += 0x7FFFu + ((u >> 16) & 1u);   // RNE
  return (unsigned short)(u >> 16);
}

// weight [co][ci][3][3] f32 -> w3 granules:
// g = shift*128 + cic*32 + qm*16 + kk*8 + wm*2 + mi ; elem = g*512 + l*8 + e
// co = qm*128 + wm*32 + mi*16 + (l&15) ; ci = cic*64 + kk*32 + (l>>4)*8 + e
__global__ void prep_w_kernel(const float* __restrict__ w, unsigned short* __restrict__ w3) {
  int i = blockIdx.x * 256 + threadIdx.x;
  if (i >= W3_ELEMS) return;
  int e = i & 7, l = (i >> 3) & 63, g = i >> 9;
  int mi = g & 1, wm = (g >> 1) & 3, kk = (g >> 3) & 1;
  int qm = (g >> 4) & 1, cic = (g >> 5) & 3, shift = g >> 7;
  int co = qm * 128 + wm * 32 + mi * 16 + (l & 15);
  int ci = cic * 64 + kk * 32 + (l >> 4) * 8 + e;
  w3[i] = f2bf(w[(co * 256 + ci) * 9 + shift]);
}

// zero the padded border of xp
__global__ void zero_border(unsigned short* __restrict__ xp) {
  int g = blockIdx.x * 256 + threadIdx.x;
  int pos = g >> 5;
  int c = (g & 31) << 3;
  int n = pos / 644;
  int p = pos - n * 644;
  int y, x;
  if (p < 324) { y = (p < 162) ? 0 : 161; x = (p < 162) ? p : p - 162; }
  else { int q = p - 324; y = 1 + (q >> 1); x = (q & 1) ? 161 : 0; }
  unsigned short* d = xp + (((size_t)(n * 162 + y)) * 162 + x) * 256 + c;
  *(uint4*)d = (uint4){0u, 0u, 0u, 0u};
}

// ori [n][ci][h][w] f32 * mask -> xp [n][h+1][w+1][ci] bf16 (padded NHWC)
__global__ void prep_x_kernel(const float* __restrict__ ori, const int* __restrict__ mask,
                              unsigned short* __restrict__ xp) {
  int bid = blockIdx.x;                 // ((n*160+h)*4+cit)*3+wt
  int wt = bid % 3;
  int t1 = bid / 3;
  int cit = t1 & 3;
  int t2 = t1 >> 2;
  int h = t2 % Hh;
  int n = t2 / Hh;
  int t = threadIdx.x;

  __shared__ float tile[64][65];

  int wl = t & 63;
  int w = wt * 64 + wl;
  bool valid = (w < Ww);
  float m = 0.f;
  if (valid) m = (float)mask[(n * Hh + h) * Ww + w];
  const float* src = ori + (((size_t)(n * CI + cit * 64) * Hh + h) * Ww + w);
  int r0 = t >> 6;
#pragma unroll
  for (int k = 0; k < 16; ++k) {
    int ci_l = r0 * 16 + k;
    float v = 0.f;
    if (valid) v = src[(size_t)ci_l * HWp] * m;
    tile[ci_l][wl] = v;
  }
  __syncthreads();

  int wl2 = t >> 2;
  int wo = wt * 64 + wl2;
  if (wo < Ww) {
    int cseg = (t & 3) * 16;
    union { unsigned short u[8]; uint4 v; } p0, p1;
#pragma unroll
    for (int j = 0; j < 8; ++j) p0.u[j] = f2bf(tile[cseg + j][wl2]);
#pragma unroll
    for (int j = 0; j < 8; ++j) p1.u[j] = f2bf(tile[cseg + 8 + j][wl2]);
    unsigned short* dst = xp + ((size_t)((n * HP + h + 1) * WP) + (wo + 1)) * CI + cit * 64 + cseg;
    *(uint4*)dst = p0.v;
    *(uint4*)(dst + 8) = p1.v;
  }
}

__device__ __forceinline__ void gload16(const unsigned short* g, unsigned short* l) {
  __builtin_amdgcn_global_load_lds((const __attribute__((address_space(1))) void*)g,
                                   (__attribute__((address_space(3))) void*)l, 16, 0, 0);
}

// Implicit GEMM: A(weights) direct-to-reg from w3 (L2-hot), B(pixels) LDS-only.
// Block 256co x 160px (one image row), BK=64, 256 thr = 4 waves (4M x 1N),
// per-wave 64co x 160px, acc[qm][mi][qn][ni] = [2][2][2][5] f32x4.
// Phases per tile: (qm,qn) = (0,0),(1,0),(1,1),(0,1); 10 B-reads + 20 MFMA each.
// B halves (80px) double-buffered: B1(t+1) staged @p0, B0(t+2) @p2 (6-phase lead);
// per-phase uniform s_waitcnt vmcnt(12) + s_barrier (counted, never 0).
// LDS 40KB -> 2 blocks/CU; grid 1280 = exactly 5 rounds, 0 tail.
__global__ void __launch_bounds__(256, 2)
sconv_gemm(const unsigned short* __restrict__ xp, const unsigned short* __restrict__ w3,
           const float* __restrict__ bias, float* __restrict__ out) {
  __shared__ unsigned short Bs[4 * 5120];   // [buf2][qn2][80 rows][64 ci] = 40KB

  const int bid = blockIdx.x;
  const int n = bid & 7;          // image per XCD
  const int h = bid >> 3;         // output row

  const int t = threadIdx.x;
  const int l = t & 63;
  const int wv = t >> 6;          // wm = wv (4M x 1N)

  const int lr = l >> 3;
  const int swz8 = ((l & 7) ^ lr) << 3;     // proven source pre-swizzle (shorts)
  const int lc = l & 15, hi4 = l >> 4, lx7 = l & 7;
  const unsigned xrow = (unsigned)(n * HP + h);

  // B staging: wave wv covers rows [basej, basej+ng*8), ng = 3,3,2,2
  const int basej = (wv < 2) ? wv * 24 : 48 + (wv - 2) * 16;
  const unsigned bof0 = (unsigned)(basej + 0 + lr) * 256 + swz8;
  const unsigned bof1 = (unsigned)(basej + 8 + lr) * 256 + swz8;
  const unsigned bof2 = (unsigned)(basej + 16 + lr) * 256 + swz8;

  f32x4 acc[2][2][2][5];
#pragma unroll
  for (int a = 0; a < 2; ++a)
#pragma unroll
    for (int b = 0; b < 2; ++b)
#pragma unroll
      for (int c = 0; c < 2; ++c)
#pragma unroll
        for (int d = 0; d < 5; ++d)
          acc[a][b][c][d] = (f32x4){0.f, 0.f, 0.f, 0.f};

  auto STAGE_B = [&](int ts, int qn) {
    int cic = (ts * 57) >> 9;              // ts/9
    int sh = ts - cic * 9;
    int kh = (sh * 11) >> 5;               // sh/3
    int kw = sh - kh * 3;
    const unsigned short* src = xp + (((size_t)(xrow + kh) * WP + kw + qn * 80) << 8) + (cic << 6);
    unsigned short* dst = (unsigned short*)Bs + ((ts & 1) * 2 + qn) * 5120 + basej * 64;
    gload16(src + bof0, dst);
    gload16(src + bof1, dst + 512);
    if (wv < 2) gload16(src + bof2, dst + 1024);
  };

  auto AG4 = [&](int ts, int qm, short8* r) {
    int cic = (ts * 57) >> 9;
    int sh = ts - cic * 9;
    const unsigned short* p = w3 + (((size_t)(sh * 128 + cic * 32 + qm * 16 + wv * 2)) << 9) + (l << 3);
    r[0] = *(const short8*)(p);                 // kk0 mi0
    r[1] = *(const short8*)(p + 512);           // kk0 mi1
    r[2] = *(const short8*)(p + 4096);          // kk1 mi0
    r[3] = *(const short8*)(p + 4096 + 512);    // kk1 mi1
  };

#define BRD(tb, qn, kk, ni) \
  (*(const short8*)((unsigned short*)Bs + ((tb) * 2 + (qn)) * 5120 + \
                    (((ni) * 16 + lc) * 64) + (((((kk) << 2) + hi4) ^ lx7) << 3)))

#define PHASE(tb, qm, qn, AREG) do { \
  _Pragma("unroll") \
  for (int kk = 0; kk < 2; ++kk) { \
    short8 bb[5]; \
    _Pragma("unroll") \
    for (int ni = 0; ni < 5; ++ni) bb[ni] = BRD(tb, qn, kk, ni); \
    __builtin_amdgcn_s_setprio(1); \
    _Pragma("unroll") \
    for (int mi = 0; mi < 2; ++mi) \
      _Pragma("unroll") \
      for (int ni = 0; ni < 5; ++ni) \
        acc[qm][mi][qn][ni] = __builtin_amdgcn_mfma_f32_16x16x32_bf16( \
            AREG[kk * 2 + mi], bb[ni], acc[qm][mi][qn][ni], 0, 0, 0); \
    __builtin_amdgcn_s_setprio(0); \
  } \
  asm volatile("s_waitcnt vmcnt(12)" ::: "memory"); \
  asm volatile("s_barrier" ::: "memory"); \
} while (0)

  short8 a0A[4], a0B[4], aQ1[4];

  // prologue: B0(0), B1(0), B0(1) staged; A(0,qm0), A(0,qm1) loaded
  STAGE_B(0, 0);
  STAGE_B(0, 1);
  STAGE_B(1, 0);
  AG4(0, 0, a0A);
  AG4(0, 1, aQ1);
  asm volatile("s_waitcnt vmcnt(12)" ::: "memory");
  asm volatile("s_barrier" ::: "memory");

  for (int tt = 0; tt < NT; tt += 2) {
    const bool n1 = (tt + 2 < NT);
    const bool n2 = (tt + 3 < NT);
    // ---- even tile (buf 0), A-qm0 in a0A ----
    STAGE_B(tt + 1, 1);                 // B1(t+1), tt+1 <= 35 always
    PHASE(0, 0, 0, a0A);
    PHASE(0, 1, 0, aQ1);
    AG4(tt + 1, 0, a0B);                // A(t+1, qm0)
    if (n1) STAGE_B(tt + 2, 0);         // B0(t+2)
    PHASE(0, 1, 1, aQ1);
    AG4(tt + 1, 1, aQ1);                // A(t+1, qm1) (after last aQ1 use)
    PHASE(0, 0, 1, a0A);
    // ---- odd tile (buf 1), A-qm0 in a0B ----
    if (n1) STAGE_B(tt + 2, 1);         // B1(t+2)
    PHASE(1, 0, 0, a0B);
    PHASE(1, 1, 0, aQ1);
    if (n1) AG4(tt + 2, 0, a0A);        // A(t+2, qm0)
    if (n2) STAGE_B(tt + 3, 0);         // B0(t+3)
    PHASE(1, 1, 1, aQ1);
    if (n1) AG4(tt + 2, 1, aQ1);        // A(t+2, qm1)
    PHASE(1, 0, 1, a0B);
  }

  // epilogue: D col(px)=l&15, row(co)=(l>>4)*4+r
#pragma unroll
  for (int qm = 0; qm < 2; ++qm)
#pragma unroll
    for (int mi = 0; mi < 2; ++mi) {
      int cobase = qm * 128 + wv * 32 + mi * 16 + hi4 * 4;
      const float4 bv = *(const float4*)(bias + cobase);
      float* op = out + (((size_t)n * CO + cobase) * Hh + h) * Ww;
#pragma unroll
      for (int qn = 0; qn < 2; ++qn)
#pragma unroll
        for (int ni = 0; ni < 5; ++ni) {
          int w = qn * 80 + ni * 16 + lc;
          f32x4 v = acc[qm][mi][qn][ni];
          op[w]                   = v[0] + bv.x;
          op[(size_t)HWp + w]     = v[1] + bv.y;
          op[(size_t)2 * HWp + w] = v[2] + bv.z;
          op[(size_t)3 * HWp + w] = v[3] + bv.w;
        }
    }
}

extern "C" void kernel_launch(void* const* d_in, const int* in_sizes, int n_in,
                              void* d_out, int out_size, void* d_ws, size_t ws_size,
                              hipStream_t stream) {
  const int* mask = (const int*)d_in[0];
  const float* ori = (const float*)d_in[1];
  const float* weight = (const float*)d_in[2];
  const float* bias = (const float*)d_in[3];
  float* out = (float*)d_out;

  unsigned short* xp = (unsigned short*)d_ws;          // padded NHWC bf16, 107.5 MB
  unsigned short* w3 = xp + XPAD_ELEMS;                // 1.2 MB granule-ordered weights

  zero_border<<<644, 256, 0, stream>>>(xp);
  prep_w_kernel<<<(W3_ELEMS + 255) / 256, 256, 0, stream>>>(weight, w3);
  prep_x_kernel<<<B_ * Hh * 4 * 3, 256, 0, stream>>>(ori, mask, xp);
  sconv_gemm<<<1280, 256, 0, stream>>>(xp, w3, bias, out);
}